// Round 1
// 1246.524 us; speedup vs baseline: 1.3417x; 1.3417x over previous
//
#include <hip/hip_runtime.h>

// Fused 2-layer GRU scan. B=256,T=1024,F=64,U=128.
// R8: restructure 4 waves -> 8 waves per block (512 thr, 2 waves/SIMD).
// Each wave now owns 16 unit-cols (1 column group) instead of 32, so the
// per-wave weight set (U1,W2,U2) is 36 frags = 144 regs and fits entirely in
// ArchVGPRs: the AGPR file (and any accvgpr_read copy tax on MFMA B-operands)
// is gone. 2 waves/SIMD lets one wave's gate-math/ds-latency hide under the
// other wave's MFMA phase (m114: MFMA+VALU pipes co-issue across waves).
// Register diet for the 256-reg/wave cap at 2 waves/EU: xw prefetch 1-ahead
// (6 regs, ~1 step of cover >> HBM latency), A2 streamed per-kt (-12 regs).
// Math, layer-2 one-step delay, parity scheme, prepass: unchanged from R7.

#define TT 1024
#define FF 64
#define G3 384
#define XW_BYTES (1024ull * 384 * 256 * 2)

typedef __attribute__((ext_vector_type(8))) __bf16 bf16x8;
typedef __attribute__((ext_vector_type(4))) float f32x4;

#define MFMA(a, b, c) __builtin_amdgcn_mfma_f32_16x16x32_bf16((a), (b), (c), 0, 0, 0)

__device__ __forceinline__ float sigf(float x) {
    return __builtin_amdgcn_rcpf(1.0f + __expf(-x));
}

__device__ __forceinline__ f32x4 unpackv(uint2 v) {
    f32x4 o;
    o[0] = __uint_as_float(v.x << 16);
    o[1] = __uint_as_float(v.x & 0xFFFF0000u);
    o[2] = __uint_as_float(v.y << 16);
    o[3] = __uint_as_float(v.y & 0xFFFF0000u);
    return o;
}

// ---- prepass: ws uint2 index = ((t*16+rb)*3+g)*512 + cg*64 + lane ---------
// slot holds batch rows quad*4..+3, unit col cg*16+lc, bf16x4 packed.
// For gates z,r BOTH input and recurrent biases are folded here; for gate h
// only the input bias (recurrent b_rh must stay separate for r*rh).
__global__ void xw_prepass(
    const float* __restrict__ x, const float* __restrict__ W1,
    const float* __restrict__ b1, unsigned short* __restrict__ ws)
{
    const int tid = threadIdx.x, wave = tid >> 6, lane = tid & 63;
    const int quad = lane >> 4, lc = lane & 15;
    const int rb = blockIdx.x;              // row block (16 rows)
    const int t  = blockIdx.y * 4 + wave;   // time step

    const float* px = x + ((size_t)(rb * 16 + lc) * TT + t) * FF + quad * 8;
    f32x4 u0 = *(const f32x4*)px;
    f32x4 u1 = *(const f32x4*)(px + 4);
    f32x4 u2 = *(const f32x4*)(px + 32);
    f32x4 u3 = *(const f32x4*)(px + 36);
    bf16x8 xa0, xa1;
#pragma unroll
    for (int j = 0; j < 4; j++) {
        xa0[j] = (__bf16)u0[j]; xa0[j + 4] = (__bf16)u1[j];
        xa1[j] = (__bf16)u2[j]; xa1[j + 4] = (__bf16)u3[j];
    }

    uint2* wq = (uint2*)ws + ((size_t)t * 16 + rb) * 1536 + lane;
    for (int nt = 0; nt < 24; nt++) {
        const int g  = nt >> 3;
        const int cg = nt & 7;
        const int uc = cg * 16 + lc;
        float bi = b1[g * 128 + uc];
        if (g < 2) bi += b1[G3 + g * 128 + uc];   // fold recurrent bias (z,r)
        bf16x8 w0, w1v;
#pragma unroll
        for (int j = 0; j < 8; j++) {
            w0[j]  = (__bf16)W1[(quad * 8 + j) * G3 + g * 128 + uc];
            w1v[j] = (__bf16)W1[(32 + quad * 8 + j) * G3 + g * 128 + uc];
        }
        f32x4 acc = {bi, bi, bi, bi};
        acc = MFMA(xa0, w0, acc);
        acc = MFMA(xa1, w1v, acc);
        unsigned int s0 = __builtin_bit_cast(unsigned short, (__bf16)acc[0]);
        unsigned int s1 = __builtin_bit_cast(unsigned short, (__bf16)acc[1]);
        unsigned int s2 = __builtin_bit_cast(unsigned short, (__bf16)acc[2]);
        unsigned int s3 = __builtin_bit_cast(unsigned short, (__bf16)acc[3]);
        uint2 st;
        st.x = s0 | (s1 << 16);
        st.y = s2 | (s3 << 16);
        wq[(size_t)(g * 8 + cg) * 64] = st;   // 512B contiguous per wave
    }
}

// ---- persistent scan kernel -----------------------------------------------
template <bool PRE>
__global__ __launch_bounds__(512, 2) void gru_persist(
    const float* __restrict__ x,  const float* __restrict__ W1,
    const float* __restrict__ U1, const float* __restrict__ b1,
    const float* __restrict__ W2, const float* __restrict__ U2,
    const float* __restrict__ b2, const unsigned short* __restrict__ xw,
    float* __restrict__ out)
{
    const int tid  = threadIdx.x;
    const int wave = tid >> 6;          // 0..7 — owns unit cols wave*16..+15
    const int lane = tid & 63;
    const int quad = lane >> 4;
    const int lc   = lane & 15;
    const int row0 = blockIdx.x * 16;
    const int u    = wave * 16 + lc;    // owned unit column

    __shared__ __align__(16) __bf16 h1s[2][16][136];
    __shared__ __align__(16) __bf16 h2s[2][16][136];
    for (int i = tid; i < 2 * 16 * 136; i += 512) {
        ((__bf16*)h1s)[i] = (__bf16)0.f;
        ((__bf16*)h2s)[i] = (__bf16)0.f;
    }

    // ---- weight B-frags: 1 column group/wave -> 36 frags = 144 VGPRs ----
    bf16x8 U1B[3][4], W2B[3][4], U2B[3][4];
    bf16x8 W1B[3][2];                   // !PRE only (dead in PRE)
#pragma unroll
    for (int g = 0; g < 3; g++) {
#pragma unroll
        for (int kt = 0; kt < 4; kt++) {
            bf16x8 a, b, c;
#pragma unroll
            for (int j = 0; j < 8; j++) {
                int k = (kt * 32 + quad * 8 + j) * G3 + g * 128 + u;
                a[j] = (__bf16)U1[k];
                b[j] = (__bf16)W2[k];
                c[j] = (__bf16)U2[k];
            }
            U1B[g][kt] = a;
            W2B[g][kt] = b;
            U2B[g][kt] = c;
        }
        if constexpr (!PRE) {
#pragma unroll
            for (int kt = 0; kt < 2; kt++) {
                bf16x8 a;
#pragma unroll
                for (int j = 0; j < 8; j++)
                    a[j] = (__bf16)W1[(kt * 32 + quad * 8 + j) * G3 + g * 128 + u];
                W1B[g][kt] = a;
            }
        }
    }

    // ---- biases (zero here; honored) ----
    float c1z  = b1[u] + b1[G3 + u];               // used only when !PRE
    float c1r  = b1[128 + u] + b1[G3 + 128 + u];   // used only when !PRE
    float b1ih = b1[256 + u];                      // used only when !PRE
    float b1rh = b1[G3 + 256 + u];
    float c2z  = b2[u] + b2[G3 + u];
    float c2r  = b2[128 + u] + b2[G3 + 128 + u];
    float b2ih = b2[256 + u];
    float b2rh = b2[G3 + 256 + u];

    // ---- xw base: uint2 index = ((t*16+rb)*3+g)*512 + wave*64 + lane ----
    const uint2* xqb = (const uint2*)xw + (size_t)blockIdx.x * 1536
                       + wave * 64 + lane;
    uint2 xwv[3];                       // 1-step-ahead prefetch buffer
    if constexpr (PRE) {
#pragma unroll
        for (int g = 0; g < 3; g++)
            xwv[g] = xqb[(size_t)g * 512];
    }
    const float* xrow = x + (size_t)(row0 + lc) * (TT * FF) + quad * 8;

    float h1c[4] = {0, 0, 0, 0};
    float h2c[4] = {0, 0, 0, 0};

    __syncthreads();

#define STEP(T, PAR)                                                           \
    {                                                                          \
        bf16x8 A1[4];                                                          \
        _Pragma("unroll") for (int kt = 0; kt < 4; kt++)                       \
            A1[kt] = *(const bf16x8*)&h1s[PAR ^ 1][lc][kt * 32 + quad * 8];    \
        f32x4 z1, r1, rh1, xh1;                                                \
        if constexpr (PRE) {                                                   \
            z1  = unpackv(xwv[0]);  /* xz incl. both biases */                 \
            r1  = unpackv(xwv[1]);                                             \
            xh1 = unpackv(xwv[2]);  /* xh incl. input bias */                  \
            rh1 = (f32x4){b1rh, b1rh, b1rh, b1rh};                             \
            if ((T) + 1 < TT) {                                                \
                _Pragma("unroll") for (int g = 0; g < 3; g++)                  \
                    xwv[g] = xqb[(size_t)((T) + 1) * 24576 + g * 512];         \
            }                                                                  \
        } else {                                                               \
            const float* px = xrow + (size_t)(T) * FF;                         \
            f32x4 u0 = *(const f32x4*)px;                                      \
            f32x4 u1 = *(const f32x4*)(px + 4);                                \
            f32x4 u2 = *(const f32x4*)(px + 32);                               \
            f32x4 u3 = *(const f32x4*)(px + 36);                               \
            bf16x8 xa0, xa1;                                                   \
            _Pragma("unroll") for (int j = 0; j < 4; j++) {                    \
                xa0[j] = (__bf16)u0[j]; xa0[j + 4] = (__bf16)u1[j];            \
                xa1[j] = (__bf16)u2[j]; xa1[j + 4] = (__bf16)u3[j];            \
            }                                                                  \
            z1  = (f32x4){c1z, c1z, c1z, c1z};                                 \
            r1  = (f32x4){c1r, c1r, c1r, c1r};                                 \
            rh1 = (f32x4){b1rh, b1rh, b1rh, b1rh};                             \
            xh1 = (f32x4){b1ih, b1ih, b1ih, b1ih};                             \
            z1  = MFMA(xa0, W1B[0][0], z1);                                    \
            z1  = MFMA(xa1, W1B[0][1], z1);                                    \
            r1  = MFMA(xa0, W1B[1][0], r1);                                    \
            r1  = MFMA(xa1, W1B[1][1], r1);                                    \
            xh1 = MFMA(xa0, W1B[2][0], xh1);                                   \
            xh1 = MFMA(xa1, W1B[2][1], xh1);                                   \
        }                                                                      \
        _Pragma("unroll") for (int kt = 0; kt < 4; kt++) {                     \
            z1  = MFMA(A1[kt], U1B[0][kt], z1);                                \
            r1  = MFMA(A1[kt], U1B[1][kt], r1);                                \
            rh1 = MFMA(A1[kt], U1B[2][kt], rh1);                               \
        }                                                                      \
        _Pragma("unroll") for (int i = 0; i < 4; i++) {                        \
            float zf = sigf(z1[i]);                                            \
            float rf = sigf(r1[i]);                                            \
            float hh = fmaxf(xh1[i] + rf * rh1[i], 0.f);                       \
            h1c[i] = fmaf(zf, h1c[i] - hh, hh);                                \
            h1s[PAR][quad * 4 + i][u] = (__bf16)h1c[i];                        \
        }                                                                      \
        f32x4 z2  = (f32x4){c2z, c2z, c2z, c2z};                               \
        f32x4 r2  = (f32x4){c2r, c2r, c2r, c2r};                               \
        f32x4 xh2 = (f32x4){b2ih, b2ih, b2ih, b2ih};                           \
        f32x4 rh2 = (f32x4){b2rh, b2rh, b2rh, b2rh};                           \
        _Pragma("unroll") for (int kt = 0; kt < 4; kt++) {                     \
            z2  = MFMA(A1[kt], W2B[0][kt], z2);                                \
            r2  = MFMA(A1[kt], W2B[1][kt], r2);                                \
            xh2 = MFMA(A1[kt], W2B[2][kt], xh2);                               \
        }                                                                      \
        _Pragma("unroll") for (int kt = 0; kt < 4; kt++) {                     \
            bf16x8 A2 = *(const bf16x8*)&h2s[PAR][lc][kt * 32 + quad * 8];     \
            z2  = MFMA(A2, U2B[0][kt], z2);                                    \
            r2  = MFMA(A2, U2B[1][kt], r2);                                    \
            rh2 = MFMA(A2, U2B[2][kt], rh2);                                   \
        }                                                                      \
        if ((T) > 0) {                                                         \
            _Pragma("unroll") for (int i = 0; i < 4; i++) {                    \
                float zf = sigf(z2[i]);                                        \
                float rf = sigf(r2[i]);                                        \
                float hh = fmaxf(xh2[i] + rf * rh2[i], 0.f);                   \
                h2c[i] = fmaf(zf, h2c[i] - hh, hh);                            \
            }                                                                  \
        }                                                                      \
        _Pragma("unroll") for (int i = 0; i < 4; i++)                          \
            h2s[PAR ^ 1][quad * 4 + i][u] = (__bf16)h2c[i];                    \
        asm volatile("s_waitcnt lgkmcnt(0)\n\ts_barrier" ::: "memory");        \
    }

    for (int t = 0; t < TT; t += 2) {
        STEP(t, 0)
        STEP(t + 1, 1)
    }
#undef STEP

    // Epilogue: h2(TT-1) from h1(TT-1) (h1s[1]) and h2(TT-2) (h2s[0])
    {
        f32x4 z2  = (f32x4){c2z, c2z, c2z, c2z};
        f32x4 r2  = (f32x4){c2r, c2r, c2r, c2r};
        f32x4 xh2 = (f32x4){b2ih, b2ih, b2ih, b2ih};
        f32x4 rh2 = (f32x4){b2rh, b2rh, b2rh, b2rh};
#pragma unroll
        for (int kt = 0; kt < 4; kt++) {
            bf16x8 a1 = *(const bf16x8*)&h1s[1][lc][kt * 32 + quad * 8];
            bf16x8 a2 = *(const bf16x8*)&h2s[0][lc][kt * 32 + quad * 8];
            z2  = MFMA(a1, W2B[0][kt], z2);
            r2  = MFMA(a1, W2B[1][kt], r2);
            xh2 = MFMA(a1, W2B[2][kt], xh2);
            z2  = MFMA(a2, U2B[0][kt], z2);
            r2  = MFMA(a2, U2B[1][kt], r2);
            rh2 = MFMA(a2, U2B[2][kt], rh2);
        }
#pragma unroll
        for (int i = 0; i < 4; i++) {
            float zf = sigf(z2[i]);
            float rf = sigf(r2[i]);
            float hh = fmaxf(xh2[i] + rf * rh2[i], 0.f);
            h2c[i] = fmaf(zf, h2c[i] - hh, hh);
        }
    }

    // out = [x = h2(T-1), state1 = h1(T-1), state2 = h2(T-1)]
#pragma unroll
    for (int i = 0; i < 4; i++) {
        int r = row0 + quad * 4 + i;
        out[(size_t)r * 128 + u]         = h2c[i];
        out[32768 + (size_t)r * 128 + u] = h1c[i];
        out[65536 + (size_t)r * 128 + u] = h2c[i];
    }
}

extern "C" void kernel_launch(void* const* d_in, const int* in_sizes, int n_in,
                              void* d_out, int out_size, void* d_ws, size_t ws_size,
                              hipStream_t stream) {
    const float* x  = (const float*)d_in[0];
    const float* W1 = (const float*)d_in[1];
    const float* U1 = (const float*)d_in[2];
    const float* b1 = (const float*)d_in[3];
    const float* W2 = (const float*)d_in[4];
    const float* U2 = (const float*)d_in[5];
    const float* b2 = (const float*)d_in[6];
    float* out = (float*)d_out;

    if (ws_size >= XW_BYTES) {
        unsigned short* ws = (unsigned short*)d_ws;
        xw_prepass<<<dim3(16, 256), dim3(256), 0, stream>>>(x, W1, b1, ws);
        gru_persist<true><<<dim3(16), dim3(512), 0, stream>>>(
            x, W1, U1, b1, W2, U2, b2, ws, out);
    } else {
        gru_persist<false><<<dim3(16), dim3(512), 0, stream>>>(
            x, W1, U1, b1, W2, U2, b2, nullptr, out);
    }
}

// Round 2
// 1245.258 us; speedup vs baseline: 1.3431x; 1.0010x over previous
//
#include <hip/hip_runtime.h>

// Fused 2-layer GRU scan. B=256,T=1024,F=64,U=128.
// R9: R8's 8-wave restructure made the per-wave weight set 36 frags = 144
// regs, but the compiler capped ArchVGPRs at 128 (VGPR_Count=128) -- chasing
// 4 waves/SIMD that the grid (16 blocks -> 1 block/CU) can never use -- and
// silently demoted the weights to AGPRs. Measured VALU issue was ~370
// inst/wave/step vs ~150 accounted: ~144 v_accvgpr_read per step, the R6
// copy tax recreated by the compiler. Fix: amdgpu_waves_per_eu(2,2) pins the
// allocator to a 256-VGPR/wave budget, and "+v" class-pins on all 36 weight
// frags force ArchVGPR residency (they fit now: 144 + ~100 working < 256).
// Structure, math, prepass: byte-identical to R8.

#define TT 1024
#define FF 64
#define G3 384
#define XW_BYTES (1024ull * 384 * 256 * 2)

typedef __attribute__((ext_vector_type(8))) __bf16 bf16x8;
typedef __attribute__((ext_vector_type(4))) float f32x4;
typedef __attribute__((ext_vector_type(4))) int i32x4;

#define MFMA(a, b, c) __builtin_amdgcn_mfma_f32_16x16x32_bf16((a), (b), (c), 0, 0, 0)
#define BCAST(w) __builtin_bit_cast(bf16x8, w)

__device__ __forceinline__ float sigf(float x) {
    return __builtin_amdgcn_rcpf(1.0f + __expf(-x));
}

__device__ __forceinline__ f32x4 unpackv(uint2 v) {
    f32x4 o;
    o[0] = __uint_as_float(v.x << 16);
    o[1] = __uint_as_float(v.x & 0xFFFF0000u);
    o[2] = __uint_as_float(v.y << 16);
    o[3] = __uint_as_float(v.y & 0xFFFF0000u);
    return o;
}

// ---- prepass: ws uint2 index = ((t*16+rb)*3+g)*512 + cg*64 + lane ---------
// slot holds batch rows quad*4..+3, unit col cg*16+lc, bf16x4 packed.
// For gates z,r BOTH input and recurrent biases are folded here; for gate h
// only the input bias (recurrent b_rh must stay separate for r*rh).
__global__ void xw_prepass(
    const float* __restrict__ x, const float* __restrict__ W1,
    const float* __restrict__ b1, unsigned short* __restrict__ ws)
{
    const int tid = threadIdx.x, wave = tid >> 6, lane = tid & 63;
    const int quad = lane >> 4, lc = lane & 15;
    const int rb = blockIdx.x;              // row block (16 rows)
    const int t  = blockIdx.y * 4 + wave;   // time step

    const float* px = x + ((size_t)(rb * 16 + lc) * TT + t) * FF + quad * 8;
    f32x4 u0 = *(const f32x4*)px;
    f32x4 u1 = *(const f32x4*)(px + 4);
    f32x4 u2 = *(const f32x4*)(px + 32);
    f32x4 u3 = *(const f32x4*)(px + 36);
    bf16x8 xa0, xa1;
#pragma unroll
    for (int j = 0; j < 4; j++) {
        xa0[j] = (__bf16)u0[j]; xa0[j + 4] = (__bf16)u1[j];
        xa1[j] = (__bf16)u2[j]; xa1[j + 4] = (__bf16)u3[j];
    }

    uint2* wq = (uint2*)ws + ((size_t)t * 16 + rb) * 1536 + lane;
    for (int nt = 0; nt < 24; nt++) {
        const int g  = nt >> 3;
        const int cg = nt & 7;
        const int uc = cg * 16 + lc;
        float bi = b1[g * 128 + uc];
        if (g < 2) bi += b1[G3 + g * 128 + uc];   // fold recurrent bias (z,r)
        bf16x8 w0, w1v;
#pragma unroll
        for (int j = 0; j < 8; j++) {
            w0[j]  = (__bf16)W1[(quad * 8 + j) * G3 + g * 128 + uc];
            w1v[j] = (__bf16)W1[(32 + quad * 8 + j) * G3 + g * 128 + uc];
        }
        f32x4 acc = {bi, bi, bi, bi};
        acc = MFMA(xa0, w0, acc);
        acc = MFMA(xa1, w1v, acc);
        unsigned int s0 = __builtin_bit_cast(unsigned short, (__bf16)acc[0]);
        unsigned int s1 = __builtin_bit_cast(unsigned short, (__bf16)acc[1]);
        unsigned int s2 = __builtin_bit_cast(unsigned short, (__bf16)acc[2]);
        unsigned int s3 = __builtin_bit_cast(unsigned short, (__bf16)acc[3]);
        uint2 st;
        st.x = s0 | (s1 << 16);
        st.y = s2 | (s3 << 16);
        wq[(size_t)(g * 8 + cg) * 64] = st;   // 512B contiguous per wave
    }
}

// ---- persistent scan kernel -----------------------------------------------
template <bool PRE>
__global__ __launch_bounds__(512)
__attribute__((amdgpu_waves_per_eu(2, 2)))
void gru_persist(
    const float* __restrict__ x,  const float* __restrict__ W1,
    const float* __restrict__ U1, const float* __restrict__ b1,
    const float* __restrict__ W2, const float* __restrict__ U2,
    const float* __restrict__ b2, const unsigned short* __restrict__ xw,
    float* __restrict__ out)
{
    const int tid  = threadIdx.x;
    const int wave = tid >> 6;          // 0..7 — owns unit cols wave*16..+15
    const int lane = tid & 63;
    const int quad = lane >> 4;
    const int lc   = lane & 15;
    const int row0 = blockIdx.x * 16;
    const int u    = wave * 16 + lc;    // owned unit column

    __shared__ __align__(16) __bf16 h1s[2][16][136];
    __shared__ __align__(16) __bf16 h2s[2][16][136];
    for (int i = tid; i < 2 * 16 * 136; i += 512) {
        ((__bf16*)h1s)[i] = (__bf16)0.f;
        ((__bf16*)h2s)[i] = (__bf16)0.f;
    }

    // ---- weight B-frags: 1 column group/wave -> 36 frags = 144 VGPRs ----
    i32x4 U1B[3][4], W2B[3][4], U2B[3][4];
    i32x4 W1B[3][2];                    // !PRE only (dead in PRE)
#pragma unroll
    for (int g = 0; g < 3; g++) {
#pragma unroll
        for (int kt = 0; kt < 4; kt++) {
            bf16x8 a, b, c;
#pragma unroll
            for (int j = 0; j < 8; j++) {
                int k = (kt * 32 + quad * 8 + j) * G3 + g * 128 + u;
                a[j] = (__bf16)U1[k];
                b[j] = (__bf16)W2[k];
                c[j] = (__bf16)U2[k];
            }
            U1B[g][kt] = __builtin_bit_cast(i32x4, a);
            W2B[g][kt] = __builtin_bit_cast(i32x4, b);
            U2B[g][kt] = __builtin_bit_cast(i32x4, c);
        }
        if constexpr (!PRE) {
#pragma unroll
            for (int kt = 0; kt < 2; kt++) {
                bf16x8 a;
#pragma unroll
                for (int j = 0; j < 8; j++)
                    a[j] = (__bf16)W1[(kt * 32 + quad * 8 + j) * G3 + g * 128 + u];
                W1B[g][kt] = __builtin_bit_cast(i32x4, a);
            }
        }
    }
    // CLASS pins: force ArchVGPR residency for every weight frag. 144 regs
    // fits the 256-VGPR/wave budget (waves_per_eu(2,2) => allocator targets
    // 256, not 128) -> MFMA B-operands read straight from VGPRs, zero
    // v_accvgpr_read in the step loop.
#pragma unroll
    for (int g = 0; g < 3; g++) {
#pragma unroll
        for (int kt = 0; kt < 4; kt++)
            asm volatile("" : "+v"(U1B[g][kt]), "+v"(W2B[g][kt]), "+v"(U2B[g][kt]));
        if constexpr (!PRE) {
#pragma unroll
            for (int kt = 0; kt < 2; kt++)
                asm volatile("" : "+v"(W1B[g][kt]));
        }
    }

    // ---- biases (zero here; honored) ----
    float c1z  = b1[u] + b1[G3 + u];               // used only when !PRE
    float c1r  = b1[128 + u] + b1[G3 + 128 + u];   // used only when !PRE
    float b1ih = b1[256 + u];                      // used only when !PRE
    float b1rh = b1[G3 + 256 + u];
    float c2z  = b2[u] + b2[G3 + u];
    float c2r  = b2[128 + u] + b2[G3 + 128 + u];
    float b2ih = b2[256 + u];
    float b2rh = b2[G3 + 256 + u];

    // ---- xw base: uint2 index = ((t*16+rb)*3+g)*512 + wave*64 + lane ----
    const uint2* xqb = (const uint2*)xw + (size_t)blockIdx.x * 1536
                       + wave * 64 + lane;
    uint2 xwv[3];                       // 1-step-ahead prefetch buffer
    if constexpr (PRE) {
#pragma unroll
        for (int g = 0; g < 3; g++)
            xwv[g] = xqb[(size_t)g * 512];
    }
    const float* xrow = x + (size_t)(row0 + lc) * (TT * FF) + quad * 8;

    float h1c[4] = {0, 0, 0, 0};
    float h2c[4] = {0, 0, 0, 0};

    __syncthreads();

#define STEP(T, PAR)                                                           \
    {                                                                          \
        bf16x8 A1[4];                                                          \
        _Pragma("unroll") for (int kt = 0; kt < 4; kt++)                       \
            A1[kt] = *(const bf16x8*)&h1s[PAR ^ 1][lc][kt * 32 + quad * 8];    \
        f32x4 z1, r1, rh1, xh1;                                                \
        if constexpr (PRE) {                                                   \
            z1  = unpackv(xwv[0]);  /* xz incl. both biases */                 \
            r1  = unpackv(xwv[1]);                                             \
            xh1 = unpackv(xwv[2]);  /* xh incl. input bias */                  \
            rh1 = (f32x4){b1rh, b1rh, b1rh, b1rh};                             \
            if ((T) + 1 < TT) {                                                \
                _Pragma("unroll") for (int g = 0; g < 3; g++)                  \
                    xwv[g] = xqb[(size_t)((T) + 1) * 24576 + g * 512];         \
            }                                                                  \
        } else {                                                               \
            const float* px = xrow + (size_t)(T) * FF;                         \
            f32x4 u0 = *(const f32x4*)px;                                      \
            f32x4 u1 = *(const f32x4*)(px + 4);                                \
            f32x4 u2 = *(const f32x4*)(px + 32);                               \
            f32x4 u3 = *(const f32x4*)(px + 36);                               \
            bf16x8 xa0, xa1;                                                   \
            _Pragma("unroll") for (int j = 0; j < 4; j++) {                    \
                xa0[j] = (__bf16)u0[j]; xa0[j + 4] = (__bf16)u1[j];            \
                xa1[j] = (__bf16)u2[j]; xa1[j + 4] = (__bf16)u3[j];            \
            }                                                                  \
            z1  = (f32x4){c1z, c1z, c1z, c1z};                                 \
            r1  = (f32x4){c1r, c1r, c1r, c1r};                                 \
            rh1 = (f32x4){b1rh, b1rh, b1rh, b1rh};                             \
            xh1 = (f32x4){b1ih, b1ih, b1ih, b1ih};                             \
            z1  = MFMA(xa0, BCAST(W1B[0][0]), z1);                             \
            z1  = MFMA(xa1, BCAST(W1B[0][1]), z1);                             \
            r1  = MFMA(xa0, BCAST(W1B[1][0]), r1);                             \
            r1  = MFMA(xa1, BCAST(W1B[1][1]), r1);                             \
            xh1 = MFMA(xa0, BCAST(W1B[2][0]), xh1);                            \
            xh1 = MFMA(xa1, BCAST(W1B[2][1]), xh1);                            \
        }                                                                      \
        _Pragma("unroll") for (int kt = 0; kt < 4; kt++) {                     \
            z1  = MFMA(A1[kt], BCAST(U1B[0][kt]), z1);                         \
            r1  = MFMA(A1[kt], BCAST(U1B[1][kt]), r1);                         \
            rh1 = MFMA(A1[kt], BCAST(U1B[2][kt]), rh1);                        \
        }                                                                      \
        _Pragma("unroll") for (int i = 0; i < 4; i++) {                        \
            float zf = sigf(z1[i]);                                            \
            float rf = sigf(r1[i]);                                            \
            float hh = fmaxf(xh1[i] + rf * rh1[i], 0.f);                       \
            h1c[i] = fmaf(zf, h1c[i] - hh, hh);                                \
            h1s[PAR][quad * 4 + i][u] = (__bf16)h1c[i];                        \
        }                                                                      \
        f32x4 z2  = (f32x4){c2z, c2z, c2z, c2z};                               \
        f32x4 r2  = (f32x4){c2r, c2r, c2r, c2r};                               \
        f32x4 xh2 = (f32x4){b2ih, b2ih, b2ih, b2ih};                           \
        f32x4 rh2 = (f32x4){b2rh, b2rh, b2rh, b2rh};                           \
        _Pragma("unroll") for (int kt = 0; kt < 4; kt++) {                     \
            z2  = MFMA(A1[kt], BCAST(W2B[0][kt]), z2);                         \
            r2  = MFMA(A1[kt], BCAST(W2B[1][kt]), r2);                         \
            xh2 = MFMA(A1[kt], BCAST(W2B[2][kt]), xh2);                        \
        }                                                                      \
        _Pragma("unroll") for (int kt = 0; kt < 4; kt++) {                     \
            bf16x8 A2 = *(const bf16x8*)&h2s[PAR][lc][kt * 32 + quad * 8];     \
            z2  = MFMA(A2, BCAST(U2B[0][kt]), z2);                             \
            r2  = MFMA(A2, BCAST(U2B[1][kt]), r2);                             \
            rh2 = MFMA(A2, BCAST(U2B[2][kt]), rh2);                            \
        }                                                                      \
        if ((T) > 0) {                                                         \
            _Pragma("unroll") for (int i = 0; i < 4; i++) {                    \
                float zf = sigf(z2[i]);                                        \
                float rf = sigf(r2[i]);                                        \
                float hh = fmaxf(xh2[i] + rf * rh2[i], 0.f);                   \
                h2c[i] = fmaf(zf, h2c[i] - hh, hh);                            \
            }                                                                  \
        }                                                                      \
        _Pragma("unroll") for (int i = 0; i < 4; i++)                          \
            h2s[PAR ^ 1][quad * 4 + i][u] = (__bf16)h2c[i];                    \
        asm volatile("s_waitcnt lgkmcnt(0)\n\ts_barrier" ::: "memory");        \
    }

    for (int t = 0; t < TT; t += 2) {
        STEP(t, 0)
        STEP(t + 1, 1)
    }
#undef STEP

    // Epilogue: h2(TT-1) from h1(TT-1) (h1s[1]) and h2(TT-2) (h2s[0])
    {
        f32x4 z2  = (f32x4){c2z, c2z, c2z, c2z};
        f32x4 r2  = (f32x4){c2r, c2r, c2r, c2r};
        f32x4 xh2 = (f32x4){b2ih, b2ih, b2ih, b2ih};
        f32x4 rh2 = (f32x4){b2rh, b2rh, b2rh, b2rh};
#pragma unroll
        for (int kt = 0; kt < 4; kt++) {
            bf16x8 a1 = *(const bf16x8*)&h1s[1][lc][kt * 32 + quad * 8];
            bf16x8 a2 = *(const bf16x8*)&h2s[0][lc][kt * 32 + quad * 8];
            z2  = MFMA(a1, BCAST(W2B[0][kt]), z2);
            r2  = MFMA(a1, BCAST(W2B[1][kt]), r2);
            xh2 = MFMA(a1, BCAST(W2B[2][kt]), xh2);
            z2  = MFMA(a2, BCAST(U2B[0][kt]), z2);
            r2  = MFMA(a2, BCAST(U2B[1][kt]), r2);
            rh2 = MFMA(a2, BCAST(U2B[2][kt]), rh2);
        }
#pragma unroll
        for (int i = 0; i < 4; i++) {
            float zf = sigf(z2[i]);
            float rf = sigf(r2[i]);
            float hh = fmaxf(xh2[i] + rf * rh2[i], 0.f);
            h2c[i] = fmaf(zf, h2c[i] - hh, hh);
        }
    }

    // out = [x = h2(T-1), state1 = h1(T-1), state2 = h2(T-1)]
#pragma unroll
    for (int i = 0; i < 4; i++) {
        int r = row0 + quad * 4 + i;
        out[(size_t)r * 128 + u]         = h2c[i];
        out[32768 + (size_t)r * 128 + u] = h1c[i];
        out[65536 + (size_t)r * 128 + u] = h2c[i];
    }
}

extern "C" void kernel_launch(void* const* d_in, const int* in_sizes, int n_in,
                              void* d_out, int out_size, void* d_ws, size_t ws_size,
                              hipStream_t stream) {
    const float* x  = (const float*)d_in[0];
    const float* W1 = (const float*)d_in[1];
    const float* U1 = (const float*)d_in[2];
    const float* b1 = (const float*)d_in[3];
    const float* W2 = (const float*)d_in[4];
    const float* U2 = (const float*)d_in[5];
    const float* b2 = (const float*)d_in[6];
    float* out = (float*)d_out;

    if (ws_size >= XW_BYTES) {
        unsigned short* ws = (unsigned short*)d_ws;
        xw_prepass<<<dim3(16, 256), dim3(256), 0, stream>>>(x, W1, b1, ws);
        gru_persist<true><<<dim3(16), dim3(512), 0, stream>>>(
            x, W1, U1, b1, W2, U2, b2, ws, out);
    } else {
        gru_persist<false><<<dim3(16), dim3(512), 0, stream>>>(
            x, W1, U1, b1, W2, U2, b2, nullptr, out);
    }
}